// Round 2
// baseline (461.640 us; speedup 1.0000x reference)
//
#include <hip/hip_runtime.h>
#include <math.h>

// Problem constants (match reference): B=65536, D_IN=1024, D_OUT=1024, 4 qubits, 1 layer.
#define D_IN_K  1024
#define D_OUT_K 1024

static constexpr float PI_F    = 3.14159265358979323846f;
static constexpr float RSQRT2  = 0.70710678118654752440f;

__device__ __forceinline__ float dot4(float4 a, float4 b, float acc) {
    return fmaf(a.x, b.x, fmaf(a.y, b.y, fmaf(a.z, b.z, fmaf(a.w, b.w, acc))));
}

// ---------------------------------------------------------------------------
// Fully fused kernel, lane-parallel circuit. 16 rows per 256-thread block.
//
//  Lane layout inside each wave (64 lanes):  lane = g*16 + amp
//    g   = lane>>4  : which of the wave's 4 rows this lane serves
//    amp = lane&15  : which of the 16 statevector amplitudes it owns
//
//  Phase 1 (pre GEMV): wave w owns rows wrow0..+3, float4 loads, 4 rows/wave.
//    Reduction: 2 cross-group butterfly steps (^16,^32) + per-lane row select
//    + 4-step in-group butterfly -> every lane holds its row's 4 sums.
//  Phase 2 (circuit): encode stage is a PRODUCT STATE -> each lane's
//    amplitude = product of 4 per-qubit 2-vectors, computed algebraically
//    (cos(atan f)=1/sqrt(1+f^2), half-angle identities; no atan/sincos).
//    CNOT = one __shfl permutation. Rot = shfl_xor + 8 FMA. Z expectation =
//    signed 4-step butterfly within the 16-lane group. z -> 256B LDS.
//  Phase 3 (post GEMV): thread t owns out columns 4t..4t+3 -> float4 stores;
//    post_w rows 4t..4t+3 preloaded at kernel start (in flight under phase 1).
//
// d_ws intentionally unused (h and z never touch global memory).
// ---------------------------------------------------------------------------
__global__ __launch_bounds__(256) void fused_kernel(
    const float* __restrict__ x, const float* __restrict__ pw,
    const float* __restrict__ pb, const float* __restrict__ qw,
    const float* __restrict__ postw, const float* __restrict__ postb,
    float* __restrict__ out, int B)
{
    const int t    = threadIdx.x;
    const int wave = t >> 6;
    const int lane = t & 63;
    const int amp  = lane & 15;               // statevector index owned
    const int g    = lane >> 4;               // row-group within wave
    const int row0  = blockIdx.x * 16;        // block's first row
    const int wrow0 = row0 + wave * 4;        // wave's first row
    if (row0 >= B) return;

    __shared__ float4 zlds[16];

    // ---- Phase-3 weights issued early: thread t -> post_w rows 4t..4t+3 ----
    const float4* pwv4 = reinterpret_cast<const float4*>(postw);
    float4 w[4];
#pragma unroll
    for (int j = 0; j < 4; ++j) w[j] = pwv4[4 * t + j];
    float4 bias = reinterpret_cast<const float4*>(postb)[t];

    // ---- Phase 1: pre GEMV, 4 rows per wave --------------------------------
    const float4* w0 = reinterpret_cast<const float4*>(pw);
    const float4* w1 = reinterpret_cast<const float4*>(pw + D_IN_K);
    const float4* w2 = reinterpret_cast<const float4*>(pw + 2 * D_IN_K);
    const float4* w3 = reinterpret_cast<const float4*>(pw + 3 * D_IN_K);
    const float4* x0 = reinterpret_cast<const float4*>(x + (size_t)(wrow0 + 0) * D_IN_K);
    const float4* x1 = reinterpret_cast<const float4*>(x + (size_t)(wrow0 + 1) * D_IN_K);
    const float4* x2 = reinterpret_cast<const float4*>(x + (size_t)(wrow0 + 2) * D_IN_K);
    const float4* x3 = reinterpret_cast<const float4*>(x + (size_t)(wrow0 + 3) * D_IN_K);

    float acc[4][4];
#pragma unroll
    for (int r = 0; r < 4; ++r)
#pragma unroll
        for (int q = 0; q < 4; ++q) acc[r][q] = 0.f;

#pragma unroll
    for (int k = 0; k < 4; ++k) {
        const int idx = lane + (k << 6);          // float4 index 0..255
        float4 a = w0[idx], b = w1[idx], c = w2[idx], d = w3[idx];
        float4 xv;
        xv = x0[idx];
        acc[0][0] = dot4(xv, a, acc[0][0]); acc[0][1] = dot4(xv, b, acc[0][1]);
        acc[0][2] = dot4(xv, c, acc[0][2]); acc[0][3] = dot4(xv, d, acc[0][3]);
        xv = x1[idx];
        acc[1][0] = dot4(xv, a, acc[1][0]); acc[1][1] = dot4(xv, b, acc[1][1]);
        acc[1][2] = dot4(xv, c, acc[1][2]); acc[1][3] = dot4(xv, d, acc[1][3]);
        xv = x2[idx];
        acc[2][0] = dot4(xv, a, acc[2][0]); acc[2][1] = dot4(xv, b, acc[2][1]);
        acc[2][2] = dot4(xv, c, acc[2][2]); acc[2][3] = dot4(xv, d, acc[2][3]);
        xv = x3[idx];
        acc[3][0] = dot4(xv, a, acc[3][0]); acc[3][1] = dot4(xv, b, acc[3][1]);
        acc[3][2] = dot4(xv, c, acc[3][2]); acc[3][3] = dot4(xv, d, acc[3][3]);
    }

    // Cross-group reduce (^16, ^32): acc summed over {l, l^16, l^32, l^48}.
#pragma unroll
    for (int r = 0; r < 4; ++r)
#pragma unroll
        for (int q = 0; q < 4; ++q) {
            acc[r][q] += __shfl_xor(acc[r][q], 16, 64);
            acc[r][q] += __shfl_xor(acc[r][q], 32, 64);
        }

    // Per-lane row select (register cndmask, no runtime array indexing).
    float myacc[4];
#pragma unroll
    for (int q = 0; q < 4; ++q) {
        float v01 = (g & 1) ? acc[1][q] : acc[0][q];
        float v23 = (g & 1) ? acc[3][q] : acc[2][q];
        myacc[q] = (g & 2) ? v23 : v01;
    }

    // In-group all-reduce (^1..^8): every lane ends with its row's full sums.
#pragma unroll
    for (int off = 1; off < 16; off <<= 1)
#pragma unroll
        for (int q = 0; q < 4; ++q)
            myacc[q] += __shfl_xor(myacc[q], off, 64);

    // ---- Phase 2: lane-parallel 4-qubit circuit ----------------------------
    // hq = tanh(pre + b) * pi   (identical per 16-lane group; parallel)
    float hq[4];
#pragma unroll
    for (int q = 0; q < 4; ++q)
        hq[q] = tanhf(myacc[q] + pb[q]) * PI_F;

    // Per-qubit encoded state v_q = RZ(atan(f^2)) RY(atan(f)) H |0>,
    // computed algebraically:
    //   cth = cos(atan f) = 1/sqrt(1+f^2);  c = cos(atan(f)/2), s = sin(..)
    //   cal = cos(atan f^2) = 1/sqrt(1+f^4); ca, sa = half-angle (alpha>=0)
    //   v0 = r(c-s)*(ca - i sa),  v1 = r(c+s)*(ca + i sa),  r = 1/sqrt(2)
    float v0r[4], v0i[4], v1r[4], v1i[4];
#pragma unroll
    for (int q = 0; q < 4; ++q) {
        float f   = hq[q];
        float f2  = f * f;
        float cth = 1.0f / sqrtf(fmaf(f,  f,  1.f));   // cos(atan f) > 0
        float c   = sqrtf(0.5f * (1.f + cth));
        float s   = copysignf(sqrtf(fmaxf(0.5f * (1.f - cth), 0.f)), f);
        float cal = 1.0f / sqrtf(fmaf(f2, f2, 1.f));   // cos(atan f^2) > 0
        float ca  = sqrtf(0.5f * (1.f + cal));
        float sa  = sqrtf(fmaxf(0.5f * (1.f - cal), 0.f));  // alpha >= 0
        float a0  = RSQRT2 * (c - s);
        float a1  = RSQRT2 * (c + s);
        v0r[q] =  a0 * ca;  v0i[q] = -a0 * sa;
        v1r[q] =  a1 * ca;  v1i[q] =  a1 * sa;
    }

    // Lane's amplitude = product over qubits; qubit q <-> amp bit (3-q).
    float ar, ai;
    {
        float x0r = (amp & 8) ? v1r[0] : v0r[0], x0i = (amp & 8) ? v1i[0] : v0i[0];
        float x1r = (amp & 4) ? v1r[1] : v0r[1], x1i = (amp & 4) ? v1i[1] : v0i[1];
        float x2r = (amp & 2) ? v1r[2] : v0r[2], x2i = (amp & 2) ? v1i[2] : v0i[2];
        float x3r = (amp & 1) ? v1r[3] : v0r[3], x3i = (amp & 1) ? v1i[3] : v0i[3];
        float m01r = x0r * x1r - x0i * x1i;
        float m01i = x0r * x1i + x0i * x1r;
        float m23r = x2r * x3r - x2i * x3i;
        float m23i = x2r * x3i + x2i * x3r;
        ar = m01r * m23r - m01i * m23i;
        ai = m01r * m23i + m01i * m23r;
    }

    // CNOTs: new[amp] = old[amp ^ ((amp&CM)?TM:0)] — one bpermute each.
    // (masks < 16 so the permutation stays inside the 16-lane group)
    {
        int src;
        src = lane ^ ((lane & 8) ? 4 : 0);  ar = __shfl(ar, src, 64); ai = __shfl(ai, src, 64);
        src = lane ^ ((lane & 4) ? 2 : 0);  ar = __shfl(ar, src, 64); ai = __shfl(ai, src, 64);
        src = lane ^ ((lane & 2) ? 1 : 0);  ar = __shfl(ar, src, 64); ai = __shfl(ai, src, 64);
        src = lane ^ ((lane & 1) ? 8 : 0);  ar = __shfl(ar, src, 64); ai = __shfl(ai, src, 64);
    }

    // Rot gates (qubit q, mask 8>>q): uniform coefficients from qw.
    //   u00 = (ct cp, -ct sp)  u01 = (-st cm, -st sm)
    //   u10 = ( st cm, -st sm) u11 = ( ct cp,  ct sp)
    // Lane with bit b: a' = c_self*a + c_other*partner,
    //   c_self = (ct cp, ±ct sp),  c_other = (±st cm, -st sm)
#pragma unroll
    for (int q = 0; q < 4; ++q) {
        const int MASK = 8 >> q;
        float phi = qw[3 * q + 0], th = qw[3 * q + 1], om = qw[3 * q + 2];
        float st, ct, sp, cp, sm, cm;
        __sincosf(0.5f * th, &st, &ct);
        __sincosf(0.5f * (phi + om), &sp, &cp);
        __sincosf(0.5f * (phi - om), &sm, &cm);
        float br_ = __shfl_xor(ar, MASK, 64);
        float bi_ = __shfl_xor(ai, MASK, 64);
        bool  b   = (amp & MASK) != 0;
        float cr = ct * cp;
        float ci = b ? (ct * sp) : -(ct * sp);
        float dr = b ? (st * cm) : -(st * cm);
        float di = -st * sm;
        float nar = cr * ar - ci * ai + dr * br_ - di * bi_;
        float nai = cr * ai + ci * ar + dr * bi_ + di * br_;
        ar = nar; ai = nai;
    }

    // Z expectations: signed in-group butterfly (offsets 1,2,4,8).
    {
        float p  = ar * ar + ai * ai;
        float z0 = (amp & 8) ? -p : p;
        float z1 = (amp & 4) ? -p : p;
        float z2 = (amp & 2) ? -p : p;
        float z3 = (amp & 1) ? -p : p;
#pragma unroll
        for (int off = 1; off < 16; off <<= 1) {
            z0 += __shfl_xor(z0, off, 64);
            z1 += __shfl_xor(z1, off, 64);
            z2 += __shfl_xor(z2, off, 64);
            z3 += __shfl_xor(z3, off, 64);
        }
        if (amp == 0) {
            float4 zv; zv.x = z0; zv.y = z1; zv.z = z2; zv.w = z3;
            zlds[wave * 4 + g] = zv;
        }
    }
    __syncthreads();

    // ---- Phase 3: post GEMV, thread t -> columns 4t..4t+3, float4 stores ---
#pragma unroll
    for (int r = 0; r < 16; ++r) {
        float4 zr = zlds[r];                      // uniform broadcast read
        float4 o;
        o.x = fmaf(zr.x, w[0].x, fmaf(zr.y, w[0].y, fmaf(zr.z, w[0].z, fmaf(zr.w, w[0].w, bias.x))));
        o.y = fmaf(zr.x, w[1].x, fmaf(zr.y, w[1].y, fmaf(zr.z, w[1].z, fmaf(zr.w, w[1].w, bias.y))));
        o.z = fmaf(zr.x, w[2].x, fmaf(zr.y, w[2].y, fmaf(zr.z, w[2].z, fmaf(zr.w, w[2].w, bias.z))));
        o.w = fmaf(zr.x, w[3].x, fmaf(zr.y, w[3].y, fmaf(zr.z, w[3].z, fmaf(zr.w, w[3].w, bias.w))));
        reinterpret_cast<float4*>(out + (size_t)(row0 + r) * D_OUT_K)[t] = o;
    }
}

// ---------------------------------------------------------------------------
extern "C" void kernel_launch(void* const* d_in, const int* in_sizes, int n_in,
                              void* d_out, int out_size, void* d_ws, size_t ws_size,
                              hipStream_t stream)
{
    const float* x      = (const float*)d_in[0];  // (B, 1024)
    const float* pre_w  = (const float*)d_in[1];  // (4, 1024)
    const float* pre_b  = (const float*)d_in[2];  // (4,)
    const float* qw     = (const float*)d_in[3];  // (1, 4, 3)
    const float* post_w = (const float*)d_in[4];  // (1024, 4)
    const float* post_b = (const float*)d_in[5];  // (1024,)
    float* out = (float*)d_out;                   // (B, 1024) fp32

    const int B = in_sizes[0] / D_IN_K;           // 65536

    // d_ws intentionally unused: h and z live in registers/LDS inside the
    // fused kernel.
    (void)d_ws; (void)ws_size;

    fused_kernel<<<(B + 15) / 16, 256, 0, stream>>>(
        x, pre_w, pre_b, qw, post_w, post_b, out, B);
}